// Round 6
// baseline (68.089 us; speedup 1.0000x reference)
//
#include <hip/hip_runtime.h>
#include <math.h>

// Problem constants (from reference): B=16, T=2048, N=1024, Ttot=32768
#define TTOT            32768
#define NNEUR           1024
#define NC4             256      // float4 columns per time row (4 KB/row)
#define ROWS_PER_WAVE   16       // 64 KB contiguous stream per wave
#define ROWS_PER_BLOCK  64       // 4 waves/block
#define NCHUNK          512      // TTOT / ROWS_PER_BLOCK

typedef float f32x4 __attribute__((ext_vector_type(4)));

struct SegState { float cnt, first, last, g2; };

// Associative combine of two time-adjacent segments' ISI state.
__device__ __forceinline__ SegState seg_combine(const SegState& a, const SegState& b) {
    if (a.cnt == 0.0f) return b;
    if (b.cnt == 0.0f) return a;
    SegState r;
    float gap = b.first - a.last;   // crossing ISI
    r.cnt   = a.cnt + b.cnt;
    r.first = a.first;
    r.last  = b.last;
    r.g2    = a.g2 + b.g2 + gap * gap;
    return r;
}

// Kernel 1: sequential-stream scan. Each wave reads a CONTIGUOUS 64 KB span
// (16 full rows of all 1024 neurons) so the DRAM access pattern matches a
// memcpy stream. Lane l covers float4 cols {l, l+64, l+128, l+192} -> 16
// neurons of state per lane. grid = 512 blocks (2/CU), block = 256.
__global__ __launch_bounds__(256) void k_scan(const float* __restrict__ s,
                                              float4* __restrict__ wstate) {
    const int tid  = threadIdx.x;
    const int lane = tid & 63;
    const int w    = tid >> 6;                        // wave 0..3 (time-ordered)
    const int rowbase = blockIdx.x * ROWS_PER_BLOCK + w * ROWS_PER_WAVE;

    const f32x4* s4 = reinterpret_cast<const f32x4*>(s);

    float cnt[4][4], first[4][4], last[4][4], g2[4][4];   // [p-colgroup][k-in-quad]
    #pragma unroll
    for (int p = 0; p < 4; ++p)
        #pragma unroll
        for (int k = 0; k < 4; ++k) {
            cnt[p][k] = 0.f; first[p][k] = -1.f; last[p][k] = -1.f; g2[p][k] = 0.f;
        }

    for (int rb = 0; rb < ROWS_PER_WAVE; rb += 2) {
        // Phase A: 8 independent contiguous loads (2 rows x 4 col-groups).
        f32x4 v[2][4];
        #pragma unroll
        for (int r = 0; r < 2; ++r)
            #pragma unroll
            for (int p = 0; p < 4; ++p)
                v[r][p] = s4[(size_t)(rowbase + rb + r) * NC4 + p * 64 + lane];

        // Phase B: branchy sparse update (exec-mask skips at ~2% spike rate).
        #pragma unroll
        for (int r = 0; r < 2; ++r) {
            const float tt = (float)(rowbase + rb + r);
            #pragma unroll
            for (int p = 0; p < 4; ++p)
                #pragma unroll
                for (int k = 0; k < 4; ++k) {
                    if (v[r][p][k] > 0.0f) {
                        if (cnt[p][k] > 0.0f) {
                            float gp = tt - last[p][k];
                            g2[p][k] += gp * gp;
                        } else {
                            first[p][k] = tt;
                        }
                        last[p][k] = tt;
                        cnt[p][k] += 1.0f;
                    }
                }
        }
    }

    // SoA LDS, conflict-free (lane stride 4B): [wave][k][col], 4 x 16 KiB.
    __shared__ float lcnt[4][4][256], lfirst[4][4][256], llast[4][4][256], lg2[4][4][256];
    #pragma unroll
    for (int p = 0; p < 4; ++p) {
        const int col = p * 64 + lane;
        #pragma unroll
        for (int k = 0; k < 4; ++k) {
            lcnt  [w][k][col] = cnt[p][k];
            lfirst[w][k][col] = first[p][k];
            llast [w][k][col] = last[p][k];
            lg2   [w][k][col] = g2[p][k];
        }
    }
    __syncthreads();

    // Epilogue: thread t owns col t (neurons 4t..4t+3); combine the 4 waves'
    // sub-chunks in time order; coalesced 16 KB wstate write per block.
    {
        const int col = tid;
        #pragma unroll
        for (int k = 0; k < 4; ++k) {
            SegState st = {lcnt[0][k][col], lfirst[0][k][col], llast[0][k][col], lg2[0][k][col]};
            #pragma unroll
            for (int y = 1; y < 4; ++y) {
                SegState b = {lcnt[y][k][col], lfirst[y][k][col], llast[y][k][col], lg2[y][k][col]};
                st = seg_combine(st, b);
            }
            wstate[(size_t)blockIdx.x * NNEUR + col * 4 + k] =
                make_float4(st.cnt, st.first, st.last, st.g2);
        }
    }
}

// Kernel 2: per-neuron combine across NCHUNK=512 chunk-states + CV finalize.
// Block = 256 threads, 4 neurons. Thread t handles chunks {2t, 2t+1} for all
// 4 neurons -> reads whole 64B lines (zero over-fetch), then a time-ordered
// shuffle tree across the 256 time-ordered threads.
__global__ __launch_bounds__(256) void k_combine(const float4* __restrict__ wstate,
                                                 const float* __restrict__ target,
                                                 float* __restrict__ outsq,
                                                 float* __restrict__ outvalid) {
    const int tid  = threadIdx.x;
    const int lane = tid & 63;
    const int w    = tid >> 6;
    const int n0   = blockIdx.x * 4;

    SegState st[4];
    #pragma unroll
    for (int k = 0; k < 4; ++k) st[k] = {0.f, -1.f, -1.f, 0.f};

    #pragma unroll
    for (int j = 0; j < 2; ++j) {
        const int c = tid * 2 + j;                  // ascending time per thread
        #pragma unroll
        for (int k = 0; k < 4; ++k) {
            float4 a = wstate[(size_t)c * NNEUR + n0 + k];
            SegState sb = {a.x, a.y, a.z, a.w};
            st[k] = seg_combine(st[k], sb);
        }
    }
    // Order-preserving binary tree across the 64 time-ordered lanes.
    for (int off = 1; off < 64; off <<= 1) {
        #pragma unroll
        for (int k = 0; k < 4; ++k) {
            SegState o;
            o.cnt   = __shfl_down(st[k].cnt,   off);
            o.first = __shfl_down(st[k].first, off);
            o.last  = __shfl_down(st[k].last,  off);
            o.g2    = __shfl_down(st[k].g2,    off);
            if ((lane & (2 * off - 1)) == 0) st[k] = seg_combine(st[k], o);
        }
    }
    // Cross-wave (4 waves, time-ordered) via LDS.
    __shared__ float4 lw[4][4];                     // [wave][neuron]
    if (lane == 0) {
        #pragma unroll
        for (int k = 0; k < 4; ++k)
            lw[w][k] = make_float4(st[k].cnt, st[k].first, st[k].last, st[k].g2);
    }
    __syncthreads();

    if (tid < 4) {                                  // thread k -> neuron n0+k
        const int k = tid;
        float4 a = lw[0][k];
        SegState s0 = {a.x, a.y, a.z, a.w};
        #pragma unroll
        for (int y = 1; y < 4; ++y) {
            float4 b = lw[y][k];
            SegState sb = {b.x, b.y, b.z, b.w};
            s0 = seg_combine(s0, sb);
        }
        float kk    = s0.cnt;
        float n_isi = kk - 1.0f;
        float sum_g = (kk > 0.0f) ? (s0.last - s0.first) : 0.0f;  // telescoped gap sum
        float mean  = sum_g / fmaxf(n_isi, 1.0f);
        float var   = (s0.g2 - n_isi * mean * mean) / fmaxf(n_isi - 1.0f, 1.0f);
        float sd    = sqrtf(fmaxf(var, 0.0f));
        bool valid  = (kk >= 3.0f) && (mean > 0.0f);
        float cv    = valid ? sd / mean : 0.0f;
        float d     = cv - target[n0 + k];
        outsq[n0 + k]    = valid ? d * d : 0.0f;
        outvalid[n0 + k] = valid ? 1.0f : 0.0f;
    }
}

// Kernel 3: deterministic reduction of 1024 per-neuron values -> scalar loss.
__global__ __launch_bounds__(256) void k_reduce(const float* __restrict__ outsq,
                                                const float* __restrict__ outvalid,
                                                float* __restrict__ out) {
    const int tid = threadIdx.x;
    float s = 0.f, v = 0.f;
    for (int i = tid; i < NNEUR; i += 256) {
        s += outsq[i];
        v += outvalid[i];
    }
    for (int off = 32; off > 0; off >>= 1) {
        s += __shfl_down(s, off);
        v += __shfl_down(v, off);
    }
    __shared__ float ls[4], lv[4];
    const int w = tid >> 6;
    if ((tid & 63) == 0) { ls[w] = s; lv[w] = v; }
    __syncthreads();
    if (tid == 0) {
        float S = ls[0] + ls[1] + ls[2] + ls[3];
        float V = lv[0] + lv[1] + lv[2] + lv[3];
        out[0] = (V > 0.0f) ? S / fmaxf(V, 1.0f) : 0.0f;
    }
}

extern "C" void kernel_launch(void* const* d_in, const int* in_sizes, int n_in,
                              void* d_out, int out_size, void* d_ws, size_t ws_size,
                              hipStream_t stream) {
    const float* spikes = (const float*)d_in[0];   // (B*T*N) fp32
    const float* target = (const float*)d_in[1];   // (N,) fp32
    float* out = (float*)d_out;

    // Workspace layout:
    //  [0, 8MB)   : float4 wstate[NCHUNK * NNEUR]
    //  [+4KB)     : float outsq[NNEUR]
    //  [+4KB)     : float outvalid[NNEUR]
    char* wsb = (char*)d_ws;
    float4* wstate   = (float4*)wsb;
    float*  outsq    = (float*)(wsb + (size_t)NCHUNK * NNEUR * sizeof(float4));
    float*  outvalid = outsq + NNEUR;

    k_scan<<<NCHUNK, 256, 0, stream>>>(spikes, wstate);
    k_combine<<<NNEUR / 4, 256, 0, stream>>>(wstate, target, outsq, outvalid);
    k_reduce<<<1, 256, 0, stream>>>(outsq, outvalid, out);
}

// Round 7
// 51.486 us; speedup vs baseline: 1.3225x; 1.3225x over previous
//
#include <hip/hip_runtime.h>
#include <math.h>

// Problem constants (from reference): B=16, T=2048, N=1024, Ttot=32768
#define TTOT   32768
#define NNEUR  1024
#define NCHUNK 256            // time chunks of 128 steps
#define SUBLEN 32             // time steps per thread (4 sub-chunks per block)
#define NC4    (NNEUR / 4)    // 256 float4 columns per time row

struct SegState { float cnt, first, last, g2; };

// Associative combine of two time-adjacent segments' ISI state.
__device__ __forceinline__ SegState seg_combine(const SegState& a, const SegState& b) {
    if (a.cnt == 0.0f) return b;
    if (b.cnt == 0.0f) return a;
    SegState r;
    float gap = b.first - a.last;   // crossing ISI
    r.cnt   = a.cnt + b.cnt;
    r.first = a.first;
    r.last  = b.last;
    r.g2    = a.g2 + b.g2 + gap * gap;
    return r;
}

// Kernel 1: streaming segmented scan — BYTE-IDENTICAL structure to round 1's
// proven 34.7 µs version (grid (4,256), block 256, branchy loop, unroll 4).
// Only addition: one thread resets the finalize counter for kernel 2.
__global__ __launch_bounds__(256) void k_scan(const float* __restrict__ s,
                                              float4* __restrict__ wstate,
                                              unsigned int* __restrict__ counter) {
    if (blockIdx.x == 0 && blockIdx.y == 0 && threadIdx.x == 0) *counter = 0u;

    const int tid  = threadIdx.x;
    const int ccol = tid & 63;
    const int ysl  = tid >> 6;
    const int col4 = blockIdx.x * 64 + ccol;       // float4 column index
    const int t0   = blockIdx.y * 128 + ysl * SUBLEN;

    const float4* s4 = reinterpret_cast<const float4*>(s);

    float cnt[4]   = {0.f, 0.f, 0.f, 0.f};
    float first[4] = {-1.f, -1.f, -1.f, -1.f};
    float last[4]  = {-1.f, -1.f, -1.f, -1.f};
    float g2[4]    = {0.f, 0.f, 0.f, 0.f};

    #pragma unroll 4
    for (int i = 0; i < SUBLEN; ++i) {
        const int t = t0 + i;
        const float4 v = s4[(size_t)t * NC4 + col4];   // coalesced 1 KiB/wave
        const float tt = (float)t;
        float vals[4] = {v.x, v.y, v.z, v.w};
        #pragma unroll
        for (int j = 0; j < 4; ++j) {
            if (vals[j] > 0.0f) {
                if (cnt[j] > 0.0f) {
                    float g = tt - last[j];
                    g2[j] += g * g;
                } else {
                    first[j] = tt;
                }
                last[j] = tt;
                cnt[j] += 1.0f;
            }
        }
    }

    // Time-ordered combine of the 4 sub-chunks per neuron via LDS.
    __shared__ float4 lds[4][64][4];   // 16 KiB
    #pragma unroll
    for (int j = 0; j < 4; ++j)
        lds[ysl][ccol][j] = make_float4(cnt[j], first[j], last[j], g2[j]);
    __syncthreads();

    if (ysl == 0) {
        #pragma unroll
        for (int j = 0; j < 4; ++j) {
            float4 a = lds[0][ccol][j];
            SegState st = {a.x, a.y, a.z, a.w};
            #pragma unroll
            for (int y = 1; y < 4; ++y) {
                float4 b = lds[y][ccol][j];
                SegState sb = {b.x, b.y, b.z, b.w};
                st = seg_combine(st, sb);
            }
            wstate[(size_t)blockIdx.y * NNEUR + col4 * 4 + j] =
                make_float4(st.cnt, st.first, st.last, st.g2);
        }
    }
}

// Kernel 2: per-neuron combine across NCHUNK chunk-states + CV finalize +
// fused deterministic final reduction (last-block-done).
// 256 blocks; one wave per neuron; the single change vs round 1's tail is
// that the 1024->1 reduction rides in the last-arriving block instead of a
// third kernel dispatch.
__global__ __launch_bounds__(256) void k_finalize(const float4* __restrict__ wstate,
                                                  const float* __restrict__ target,
                                                  float* __restrict__ outsq,
                                                  float* __restrict__ outvalid,
                                                  unsigned int* __restrict__ counter,
                                                  float* __restrict__ out) {
    const int tid  = threadIdx.x;
    const int lane = tid & 63;
    const int w    = tid >> 6;
    const int n    = blockIdx.x * 4 + w;

    SegState st = {0.f, -1.f, -1.f, 0.f};
    #pragma unroll
    for (int j = 0; j < NCHUNK / 64; ++j) {
        int c = lane * (NCHUNK / 64) + j;          // ascending time order per lane
        float4 a = wstate[(size_t)c * NNEUR + n];
        SegState sb = {a.x, a.y, a.z, a.w};
        st = seg_combine(st, sb);
    }
    // Order-preserving binary tree reduction across 64 lanes.
    for (int off = 1; off < 64; off <<= 1) {
        SegState o;
        o.cnt   = __shfl_down(st.cnt,   off);
        o.first = __shfl_down(st.first, off);
        o.last  = __shfl_down(st.last,  off);
        o.g2    = __shfl_down(st.g2,    off);
        if ((lane & (2 * off - 1)) == 0) st = seg_combine(st, o);
    }

    if (lane == 0) {
        float k     = st.cnt;
        float n_isi = k - 1.0f;
        float sum_g = (k > 0.0f) ? (st.last - st.first) : 0.0f;  // telescoped gap sum
        float mean  = sum_g / fmaxf(n_isi, 1.0f);
        float var   = (st.g2 - n_isi * mean * mean) / fmaxf(n_isi - 1.0f, 1.0f);
        float sd    = sqrtf(fmaxf(var, 0.0f));
        bool valid  = (k >= 3.0f) && (mean > 0.0f);
        float cv    = valid ? sd / mean : 0.0f;
        float d     = cv - target[n];
        outsq[n]    = valid ? d * d : 0.0f;
        outvalid[n] = valid ? 1.0f : 0.0f;
        __threadfence();   // agent-scope: publish my stores before arrival
    }
    __syncthreads();

    __shared__ unsigned int oldc;
    if (tid == 0) oldc = atomicAdd(counter, 1u);
    __syncthreads();

    if (oldc == gridDim.x - 1) {                   // last block to arrive
        __threadfence();                           // acquire other blocks' stores
        float ssum = 0.f, vsum = 0.f;
        for (int i = tid; i < NNEUR; i += 256) { ssum += outsq[i]; vsum += outvalid[i]; }
        for (int off = 32; off > 0; off >>= 1) {
            ssum += __shfl_down(ssum, off);
            vsum += __shfl_down(vsum, off);
        }
        __shared__ float ls[4], lv[4];
        if (lane == 0) { ls[w] = ssum; lv[w] = vsum; }
        __syncthreads();
        if (tid == 0) {
            float S = ls[0] + ls[1] + ls[2] + ls[3];
            float V = lv[0] + lv[1] + lv[2] + lv[3];
            out[0] = (V > 0.0f) ? S / fmaxf(V, 1.0f) : 0.0f;
        }
    }
}

extern "C" void kernel_launch(void* const* d_in, const int* in_sizes, int n_in,
                              void* d_out, int out_size, void* d_ws, size_t ws_size,
                              hipStream_t stream) {
    const float* spikes = (const float*)d_in[0];   // (B*T*N) fp32
    const float* target = (const float*)d_in[1];   // (N,) fp32
    float* out = (float*)d_out;

    // Workspace layout:
    //  [0, 4MB)   : float4 wstate[NCHUNK * NNEUR]
    //  [+4KB)     : float outsq[NNEUR]
    //  [+4KB)     : float outvalid[NNEUR]
    //  [+4B]      : unsigned int counter (reset by k_scan every call)
    char* wsb = (char*)d_ws;
    float4* wstate   = (float4*)wsb;
    float*  outsq    = (float*)(wsb + (size_t)NCHUNK * NNEUR * sizeof(float4));
    float*  outvalid = outsq + NNEUR;
    unsigned int* counter = (unsigned int*)(outvalid + NNEUR);

    dim3 g1(NNEUR / 256, NCHUNK);
    k_scan<<<g1, 256, 0, stream>>>(spikes, wstate, counter);
    k_finalize<<<NNEUR / 4, 256, 0, stream>>>(wstate, target, outsq, outvalid, counter, out);
}

// Round 8
// 34.929 us; speedup vs baseline: 1.9493x; 1.4740x over previous
//
#include <hip/hip_runtime.h>
#include <math.h>

// Problem constants (from reference): B=16, T=2048, N=1024, Ttot=32768
#define TTOT   32768
#define NNEUR  1024
#define NCHUNK 256            // time chunks of 128 steps
#define SUBLEN 32             // time steps per thread = one 32-bit mask window
#define NC4    (NNEUR / 4)    // 256 float4 columns per time row

struct SegState { float cnt, first, last, g2; };

// Associative combine of two time-adjacent segments' ISI state.
__device__ __forceinline__ SegState seg_combine(const SegState& a, const SegState& b) {
    if (a.cnt == 0.0f) return b;
    if (b.cnt == 0.0f) return a;
    SegState r;
    float gap = b.first - a.last;   // crossing ISI
    r.cnt   = a.cnt + b.cnt;
    r.first = a.first;
    r.last  = b.last;
    r.g2    = a.g2 + b.g2 + gap * gap;
    return r;
}

// Kernel 1: streaming segmented scan, bit-pack edition.
// grid = (NNEUR/256, NCHUNK) = (4,256), block = 256 — identical shape to the
// proven round-1 config. Per thread: 32 rows x 4 neurons.
// Phase 1: branch-free pack of spike flags (bit 23 of 1.0f) into four 32-bit
// masks (2 VALU/element). Phase 2: decode each mask ONCE via popc/ctz/clz +
// a ~0.65-iteration gap loop. This cuts per-byte instruction cost ~7x vs the
// per-row branchy update, which the issue-bound model says was the limiter.
__global__ __launch_bounds__(256) void k_scan(const float* __restrict__ s,
                                              float4* __restrict__ wstate) {
    const int tid  = threadIdx.x;
    const int ccol = tid & 63;
    const int ysl  = tid >> 6;
    const int col4 = blockIdx.x * 64 + ccol;       // float4 column index
    const int t0   = blockIdx.y * 128 + ysl * SUBLEN;

    const uint4* s4 = reinterpret_cast<const uint4*>(s);

    unsigned int m0 = 0u, m1 = 0u, m2 = 0u, m3 = 0u;

    // Phase 1: 4 batches of 8 independent loads, then straight-line packing.
    for (int g = 0; g < 4; ++g) {
        uint4 v[8];
        #pragma unroll
        for (int i = 0; i < 8; ++i)
            v[i] = s4[(size_t)(t0 + g * 8 + i) * NC4 + col4];   // coalesced 1 KiB/wave
        #pragma unroll
        for (int i = 0; i < 8; ++i) {
            const int rb = g * 8 + i;
            m0 |= ((v[i].x >> 23) & 1u) << rb;   // bit23 set iff value == 1.0f
            m1 |= ((v[i].y >> 23) & 1u) << rb;
            m2 |= ((v[i].z >> 23) & 1u) << rb;
            m3 |= ((v[i].w >> 23) & 1u) << rb;
        }
    }

    // Phase 2: decode each neuron's 32-step window mask into a SegState.
    const unsigned int m[4] = {m0, m1, m2, m3};
    float cnt[4], first[4], last[4], g2[4];
    #pragma unroll
    for (int j = 0; j < 4; ++j) {
        const unsigned int mask = m[j];
        if (mask) {
            cnt[j] = (float)__popc(mask);
            const int fr = __builtin_ctz(mask);
            const int lr = 31 - __builtin_clz(mask);
            first[j] = (float)(t0 + fr);
            last[j]  = (float)(t0 + lr);
            float acc = 0.f;
            unsigned int mm = mask & (mask - 1u);   // drop first spike
            int prevp = fr;
            while (mm) {                             // ~0.65 iterations on average
                const int p = __builtin_ctz(mm);
                mm &= mm - 1u;
                const int d = p - prevp;             // gap in steps (<=31, exact)
                acc += (float)(d * d);
                prevp = p;
            }
            g2[j] = acc;
        } else {
            cnt[j] = 0.f; first[j] = -1.f; last[j] = -1.f; g2[j] = 0.f;
        }
    }

    // Time-ordered combine of the 4 sub-chunks per neuron via LDS (as round 1).
    __shared__ float4 lds[4][64][4];   // 16 KiB
    #pragma unroll
    for (int j = 0; j < 4; ++j)
        lds[ysl][ccol][j] = make_float4(cnt[j], first[j], last[j], g2[j]);
    __syncthreads();

    if (ysl == 0) {
        #pragma unroll
        for (int j = 0; j < 4; ++j) {
            float4 a = lds[0][ccol][j];
            SegState st = {a.x, a.y, a.z, a.w};
            #pragma unroll
            for (int y = 1; y < 4; ++y) {
                float4 b = lds[y][ccol][j];
                SegState sb = {b.x, b.y, b.z, b.w};
                st = seg_combine(st, sb);
            }
            wstate[(size_t)blockIdx.y * NNEUR + col4 * 4 + j] =
                make_float4(st.cnt, st.first, st.last, st.g2);
        }
    }
}

// Kernel 2: per-neuron combine across NCHUNK chunk-states + finalize CV.
// One wave (64 lanes) per neuron; block = 256 threads = 4 neurons. (Round-1
// verbatim — each block's 4 neurons share whole 64B wstate lines.)
__global__ __launch_bounds__(256) void k_combine(const float4* __restrict__ wstate,
                                                 const float* __restrict__ target,
                                                 float* __restrict__ outsq,
                                                 float* __restrict__ outvalid) {
    const int tid  = threadIdx.x;
    const int lane = tid & 63;
    const int w    = tid >> 6;
    const int n    = blockIdx.x * 4 + w;

    SegState st = {0.f, -1.f, -1.f, 0.f};
    #pragma unroll
    for (int j = 0; j < NCHUNK / 64; ++j) {
        int c = lane * (NCHUNK / 64) + j;          // ascending time order per lane
        float4 a = wstate[(size_t)c * NNEUR + n];
        SegState sb = {a.x, a.y, a.z, a.w};
        st = seg_combine(st, sb);
    }
    // Order-preserving binary tree reduction across 64 lanes.
    for (int off = 1; off < 64; off <<= 1) {
        SegState o;
        o.cnt   = __shfl_down(st.cnt,   off);
        o.first = __shfl_down(st.first, off);
        o.last  = __shfl_down(st.last,  off);
        o.g2    = __shfl_down(st.g2,    off);
        if ((lane & (2 * off - 1)) == 0) st = seg_combine(st, o);
    }

    if (lane == 0) {
        float k     = st.cnt;
        float n_isi = k - 1.0f;
        float sum_g = (k > 0.0f) ? (st.last - st.first) : 0.0f;  // telescoped gap sum
        float mean  = sum_g / fmaxf(n_isi, 1.0f);
        float var   = (st.g2 - n_isi * mean * mean) / fmaxf(n_isi - 1.0f, 1.0f);
        float sd    = sqrtf(fmaxf(var, 0.0f));
        bool valid  = (k >= 3.0f) && (mean > 0.0f);
        float cv    = valid ? sd / mean : 0.0f;
        float d     = cv - target[n];
        outsq[n]    = valid ? d * d : 0.0f;
        outvalid[n] = valid ? 1.0f : 0.0f;
    }
}

// Kernel 3: deterministic reduction of 1024 per-neuron values -> scalar loss.
__global__ __launch_bounds__(256) void k_reduce(const float* __restrict__ outsq,
                                                const float* __restrict__ outvalid,
                                                float* __restrict__ out) {
    const int tid = threadIdx.x;
    float s = 0.f, v = 0.f;
    for (int i = tid; i < NNEUR; i += 256) {
        s += outsq[i];
        v += outvalid[i];
    }
    for (int off = 32; off > 0; off >>= 1) {
        s += __shfl_down(s, off);
        v += __shfl_down(v, off);
    }
    __shared__ float ls[4], lv[4];
    const int w = tid >> 6;
    if ((tid & 63) == 0) { ls[w] = s; lv[w] = v; }
    __syncthreads();
    if (tid == 0) {
        float S = ls[0] + ls[1] + ls[2] + ls[3];
        float V = lv[0] + lv[1] + lv[2] + lv[3];
        out[0] = (V > 0.0f) ? S / fmaxf(V, 1.0f) : 0.0f;
    }
}

extern "C" void kernel_launch(void* const* d_in, const int* in_sizes, int n_in,
                              void* d_out, int out_size, void* d_ws, size_t ws_size,
                              hipStream_t stream) {
    const float* spikes = (const float*)d_in[0];   // (B*T*N) fp32, exactly 0.0/1.0
    const float* target = (const float*)d_in[1];   // (N,) fp32
    float* out = (float*)d_out;

    // Workspace layout:
    //  [0, 4MB)   : float4 wstate[NCHUNK * NNEUR]
    //  [+4KB)     : float outsq[NNEUR]
    //  [+4KB)     : float outvalid[NNEUR]
    char* wsb = (char*)d_ws;
    float4* wstate   = (float4*)wsb;
    float*  outsq    = (float*)(wsb + (size_t)NCHUNK * NNEUR * sizeof(float4));
    float*  outvalid = outsq + NNEUR;

    dim3 g1(NNEUR / 256, NCHUNK);
    k_scan<<<g1, 256, 0, stream>>>(spikes, wstate);
    k_combine<<<NNEUR / 4, 256, 0, stream>>>(wstate, target, outsq, outvalid);
    k_reduce<<<1, 256, 0, stream>>>(outsq, outvalid, out);
}

// Round 9
// 34.792 us; speedup vs baseline: 1.9570x; 1.0039x over previous
//
#include <hip/hip_runtime.h>
#include <math.h>

// Problem constants (from reference): B=16, T=2048, N=1024, Ttot=32768
#define TTOT   32768
#define NNEUR  1024
#define NCHUNK 256            // time chunks of 128 steps
#define NC4    (NNEUR / 4)    // 256 float4 columns per time row

struct SegState { float cnt, first, last, g2; };

// Associative combine of two time-adjacent segments' ISI state.
__device__ __forceinline__ SegState seg_combine(const SegState& a, const SegState& b) {
    if (a.cnt == 0.0f) return b;
    if (b.cnt == 0.0f) return a;
    SegState r;
    float gap = b.first - a.last;   // crossing ISI
    r.cnt   = a.cnt + b.cnt;
    r.first = a.first;
    r.last  = b.last;
    r.g2    = a.g2 + b.g2 + gap * gap;
    return r;
}

// Kernel 1: streaming segmented scan — BARRIER-FREE edition.
// grid = (NNEUR/256, NCHUNK) = (4,256), block = 256 = 4 independent waves.
// Lane remap: lane = 16*(row-group) + col. Wave w covers float4-cols
// [bx*64 + w*16, +16) over 128 rows; row-group g=lane>>4 owns rows
// [t0+32g, t0+32g+32). Each wave-load touches 4x256B = the same 8 lines a
// contiguous 1 KiB load would — coalescing unchanged. A neuron's 4
// sub-chunk states live in lanes {c, c+16, c+32, c+48} of ONE wave, so the
// time-ordered combine is 2 shuffle steps. No LDS, no __syncthreads, no
// epilogue idling: each wave streams, shuffles, stores, retires.
__global__ __launch_bounds__(256) void k_scan(const float* __restrict__ s,
                                              float4* __restrict__ wstate) {
    const int tid  = threadIdx.x;
    const int lane = tid & 63;
    const int w    = tid >> 6;
    const int g    = lane >> 4;                    // row-group 0..3 (time order)
    const int c    = lane & 15;                    // col within wave's 16-col span
    const int col4 = blockIdx.x * 64 + w * 16 + c; // float4 column index
    const int t0L  = blockIdx.y * 128 + g * 32;    // this lane's 32-row window

    const uint4* s4 = reinterpret_cast<const uint4*>(s);

    unsigned int m0 = 0u, m1 = 0u, m2 = 0u, m3 = 0u;

    // Phase 1: 4 batches of 8 independent loads + branch-free bit-pack
    // (bit 23 of the fp32 bits is set iff the value is exactly 1.0f).
    for (int b = 0; b < 4; ++b) {
        uint4 v[8];
        #pragma unroll
        for (int i = 0; i < 8; ++i)
            v[i] = s4[(size_t)(t0L + b * 8 + i) * NC4 + col4];
        #pragma unroll
        for (int i = 0; i < 8; ++i) {
            const int rb = b * 8 + i;
            m0 |= ((v[i].x >> 23) & 1u) << rb;
            m1 |= ((v[i].y >> 23) & 1u) << rb;
            m2 |= ((v[i].z >> 23) & 1u) << rb;
            m3 |= ((v[i].w >> 23) & 1u) << rb;
        }
    }

    // Phase 2: decode each neuron's 32-step mask into a SegState, then
    // combine the 4 row-groups across lanes (order-preserving: g, g+1 ...).
    const unsigned int m[4] = {m0, m1, m2, m3};
    #pragma unroll
    for (int k = 0; k < 4; ++k) {
        const unsigned int mask = m[k];
        SegState st;
        if (mask) {
            st.cnt = (float)__popc(mask);
            const int fr = __builtin_ctz(mask);
            const int lr = 31 - __builtin_clz(mask);
            st.first = (float)(t0L + fr);
            st.last  = (float)(t0L + lr);
            float acc = 0.f;
            unsigned int mm = mask & (mask - 1u);   // drop first spike
            int prevp = fr;
            while (mm) {                             // ~0.65 iterations on average
                const int p = __builtin_ctz(mm);
                mm &= mm - 1u;
                const int d = p - prevp;             // exact small-int gap
                acc += (float)(d * d);
                prevp = p;
            }
            st.g2 = acc;
        } else {
            st = {0.f, -1.f, -1.f, 0.f};
        }

        // Tree combine over row-groups: (0,1)(2,3) then (01,23).
        SegState o;
        o.cnt   = __shfl_down(st.cnt,   16);
        o.first = __shfl_down(st.first, 16);
        o.last  = __shfl_down(st.last,  16);
        o.g2    = __shfl_down(st.g2,    16);
        st = seg_combine(st, o);                     // meaningful on g=0,2
        o.cnt   = __shfl_down(st.cnt,   32);
        o.first = __shfl_down(st.first, 32);
        o.last  = __shfl_down(st.last,  32);
        o.g2    = __shfl_down(st.g2,    32);
        st = seg_combine(st, o);                     // meaningful on g=0

        if (lane < 16)                               // g==0 holds the chunk state
            wstate[(size_t)blockIdx.y * NNEUR + col4 * 4 + k] =
                make_float4(st.cnt, st.first, st.last, st.g2);
    }
}

// Kernel 2: per-neuron combine across NCHUNK chunk-states + finalize CV.
// One wave (64 lanes) per neuron; block = 256 threads = 4 neurons (round-1
// verbatim — each block's 4 neurons share whole 64B wstate lines).
__global__ __launch_bounds__(256) void k_combine(const float4* __restrict__ wstate,
                                                 const float* __restrict__ target,
                                                 float* __restrict__ outsq,
                                                 float* __restrict__ outvalid) {
    const int tid  = threadIdx.x;
    const int lane = tid & 63;
    const int w    = tid >> 6;
    const int n    = blockIdx.x * 4 + w;

    SegState st = {0.f, -1.f, -1.f, 0.f};
    #pragma unroll
    for (int j = 0; j < NCHUNK / 64; ++j) {
        int c = lane * (NCHUNK / 64) + j;          // ascending time order per lane
        float4 a = wstate[(size_t)c * NNEUR + n];
        SegState sb = {a.x, a.y, a.z, a.w};
        st = seg_combine(st, sb);
    }
    // Order-preserving binary tree reduction across 64 lanes.
    for (int off = 1; off < 64; off <<= 1) {
        SegState o;
        o.cnt   = __shfl_down(st.cnt,   off);
        o.first = __shfl_down(st.first, off);
        o.last  = __shfl_down(st.last,  off);
        o.g2    = __shfl_down(st.g2,    off);
        if ((lane & (2 * off - 1)) == 0) st = seg_combine(st, o);
    }

    if (lane == 0) {
        float k     = st.cnt;
        float n_isi = k - 1.0f;
        float sum_g = (k > 0.0f) ? (st.last - st.first) : 0.0f;  // telescoped gap sum
        float mean  = sum_g / fmaxf(n_isi, 1.0f);
        float var   = (st.g2 - n_isi * mean * mean) / fmaxf(n_isi - 1.0f, 1.0f);
        float sd    = sqrtf(fmaxf(var, 0.0f));
        bool valid  = (k >= 3.0f) && (mean > 0.0f);
        float cv    = valid ? sd / mean : 0.0f;
        float d     = cv - target[n];
        outsq[n]    = valid ? d * d : 0.0f;
        outvalid[n] = valid ? 1.0f : 0.0f;
    }
}

// Kernel 3: deterministic reduction of 1024 per-neuron values -> scalar loss.
__global__ __launch_bounds__(256) void k_reduce(const float* __restrict__ outsq,
                                                const float* __restrict__ outvalid,
                                                float* __restrict__ out) {
    const int tid = threadIdx.x;
    float s = 0.f, v = 0.f;
    for (int i = tid; i < NNEUR; i += 256) {
        s += outsq[i];
        v += outvalid[i];
    }
    for (int off = 32; off > 0; off >>= 1) {
        s += __shfl_down(s, off);
        v += __shfl_down(v, off);
    }
    __shared__ float ls[4], lv[4];
    const int w = tid >> 6;
    if ((tid & 63) == 0) { ls[w] = s; lv[w] = v; }
    __syncthreads();
    if (tid == 0) {
        float S = ls[0] + ls[1] + ls[2] + ls[3];
        float V = lv[0] + lv[1] + lv[2] + lv[3];
        out[0] = (V > 0.0f) ? S / fmaxf(V, 1.0f) : 0.0f;
    }
}

extern "C" void kernel_launch(void* const* d_in, const int* in_sizes, int n_in,
                              void* d_out, int out_size, void* d_ws, size_t ws_size,
                              hipStream_t stream) {
    const float* spikes = (const float*)d_in[0];   // (B*T*N) fp32, exactly 0.0/1.0
    const float* target = (const float*)d_in[1];   // (N,) fp32
    float* out = (float*)d_out;

    // Workspace layout:
    //  [0, 4MB)   : float4 wstate[NCHUNK * NNEUR]
    //  [+4KB)     : float outsq[NNEUR]
    //  [+4KB)     : float outvalid[NNEUR]
    char* wsb = (char*)d_ws;
    float4* wstate   = (float4*)wsb;
    float*  outsq    = (float*)(wsb + (size_t)NCHUNK * NNEUR * sizeof(float4));
    float*  outvalid = outsq + NNEUR;

    dim3 g1(NNEUR / 256, NCHUNK);
    k_scan<<<g1, 256, 0, stream>>>(spikes, wstate);
    k_combine<<<NNEUR / 4, 256, 0, stream>>>(wstate, target, outsq, outvalid);
    k_reduce<<<1, 256, 0, stream>>>(outsq, outvalid, out);
}